// Round 2
// baseline (436.041 us; speedup 1.0000x reference)
//
#include <hip/hip_runtime.h>
#include <hip/hip_bf16.h>

// Problem constants (fixed by setup_inputs)
#define M_ROWS 262144   // B*A*T = 16*64*256
#define TILE_M 64
#define BK 32
#define REP 64          // second-level stats partials (matches finalize_k layout)
#define NBLOCKS 256     // persistent fused kernel: 1 block per CU
#define INVM (1.0f / 262144.0f)

typedef unsigned short ushort_t;
typedef unsigned int uint_t;
typedef __attribute__((ext_vector_type(8))) short short8_t;   // 8 bf16 = 4 VGPRs
typedef __attribute__((ext_vector_type(4))) float float4_t;   // MFMA acc

// bf16 (stored as ushort) <-> fp32 helpers. Load is exact; store is RNE.
__device__ __forceinline__ float b2f(ushort_t u) {
    union { uint_t i; float f; } c; c.i = ((uint_t)u) << 16; return c.f;
}
__device__ __forceinline__ ushort_t f2b(float f) {
    union { float f; uint_t i; } c; c.f = f;
    uint_t u = c.i;
    return (ushort_t)((u + 0x7fffu + ((u >> 16) & 1u)) >> 16);
}
// packed 2xfp32 -> 2xbf16 (v_cvt_pk_bf16_f32 on gfx950, RNE)
__device__ __forceinline__ uint_t pack2(float a, float b) {
    union { __hip_bfloat162 h; uint_t u; } c;
    c.h = __float22bfloat162_rn(make_float2(a, b));
    return c.u;
}

// async global->LDS DMA, 16 B per lane; data lands at ldsbase + lane*16
__device__ __forceinline__ void gld_lds16(const ushort_t* g, ushort_t* l) {
    __builtin_amdgcn_global_load_lds((const __attribute__((address_space(1))) void*)g,
                                     (__attribute__((address_space(3))) void*)l, 16, 0, 0);
}

// same-wave LDS memory-memory ordering (no barrier needed: all hazards are
// within one wave; lgkmcnt(0) guarantees all prior DS ops committed)
#define LGKM0 asm volatile("s_waitcnt lgkmcnt(0)" ::: "memory")

// ---------------------------------------------------------------------------
// Persistent fused L1..L4 kernel (cooperative), wave-independent decomposition.
// 256 blocks x 512 threads. Wave-task = (sequence, N-half): 2048 tasks =
// 1024 sequences x 2 column-halves. Each wave owns a private 8 KB LDS tile
// and processes its whole sequence (8 tiles of 32 rows) with ZERO barriers in
// the tile loop (same-wave lgkmcnt ordering only). Causal cummax is in-lane
// serial (lane owns 2 columns, carry in registers). Block barriers: weight
// stage + stats per phase; 3 grid syncs for BN stats between layers.
// ---------------------------------------------------------------------------
struct __attribute__((aligned(16))) SmemT {
    ushort_t Ws[128 * 256];    // 64 KB  weight tile (N x K bf16, XOR-swizzled)
    ushort_t AW[8][4096];      // 64 KB  per-wave 8 KB tile buffers
    float    sred[1024];       //  4 KB  stats cross-wave reduce
    float    s_sc[128];
    float    s_sh[128];
};

__device__ __forceinline__ void grid_sync(unsigned* cnt) {
    __syncthreads();
    if (threadIdx.x == 0) {
        __threadfence();
        __hip_atomic_fetch_add(cnt, 1u, __ATOMIC_ACQ_REL, __HIP_MEMORY_SCOPE_AGENT);
        while (__hip_atomic_load(cnt, __ATOMIC_ACQUIRE, __HIP_MEMORY_SCOPE_AGENT) < (unsigned)NBLOCKS) {
            __builtin_amdgcn_s_sleep(2);
        }
    }
    __syncthreads();
}

__device__ __forceinline__ void compute_scsh(SmemT& sm, const float* accum,
                                             const float* g, const float* be) {
    int f = threadIdx.x;
    if (f < 128) {
        float s = __hip_atomic_load(accum + f, __ATOMIC_RELAXED, __HIP_MEMORY_SCOPE_AGENT);
        float q = __hip_atomic_load(accum + 128 + f, __ATOMIC_RELAXED, __HIP_MEMORY_SCOPE_AGENT);
        float mean = s * INVM;
        float var = q * INVM - mean * mean;
        float sc = g[f] * rsqrtf(var + 1e-5f);
        sm.s_sc[f] = sc;
        sm.s_sh[f] = fmaf(-mean, sc, be[f]);
    }
    __syncthreads();
}

// One layer pass. KW: GEMM K (256 for L1 concat, else 128). NWT: total output
// cols (128 or 64); each wave computes its nh-half (NWT/2). SCAN: causal
// cummax on act'd input. CONCAT: A = [act | cummax] (L1, two kt passes over
// the same 8 KB buffer with in-place scan between). STATS: BN partials.
template<int KW, int NWT, bool SCAN, bool CONCAT, bool STATS, bool OUTF32>
__device__ __forceinline__ void phase_run(SmemT& sm, const ushort_t* __restrict__ Yin,
                                          char* __restrict__ Yout,
                                          const ushort_t* __restrict__ WT,
                                          const float* __restrict__ bias,
                                          float* __restrict__ accum, int blockRow0) {
    constexpr int NH = NWT / 2;      // cols per wave-task (64 or 32)
    constexpr int NT = NH / 16;      // 4 or 2

    const int tid = threadIdx.x;
    const int lane = tid & 63;
    const int wave = tid >> 6;       // 0..7
    const int seqw = wave >> 1;      // local sequence 0..3
    const int nh = wave & 1;         // column half
    const int quad = lane >> 4, l16 = lane & 15;
    const int row0 = blockRow0 + seqw * 256;
    char* AWb = (char*)sm.AW[wave];

    // ---- stage weights (NWT x KW bf16) via DMA, source pre-swizzled ----
    if constexpr (KW == 256) {
        #pragma unroll
        for (int i = 0; i < 8; ++i) {
            int t = i * 8 + wave;
            int r = t * 2 + (lane >> 5);
            int jd = lane & 31;
            int js = (jd & 16) | ((jd ^ (r & 15)) & 15);
            gld_lds16(WT + (size_t)r * 256 + js * 8, sm.Ws + t * 512);
        }
    } else {
        #pragma unroll
        for (int i = 0; i < NWT / 32; ++i) {
            int t = i * 8 + wave;
            int r = t * 4 + (lane >> 4);
            int js = (lane & 15) ^ (r & 15);
            gld_lds16(WT + (size_t)r * 128 + js * 8, sm.Ws + t * 512);
        }
    }
    __syncthreads();   // weights + s_sc/s_sh resident for all waves

    // per-lane act coefficients: lane's chunk covers input cols l16*8..+7
    float scr[8], shr[8];
    #pragma unroll
    for (int e = 0; e < 8; ++e) { scr[e] = sm.s_sc[l16 * 8 + e]; shr[e] = sm.s_sh[l16 * 8 + e]; }

    float bvs[NT];
    #pragma unroll
    for (int nt = 0; nt < NT; ++nt) bvs[nt] = bias[nh * NH + nt * 16 + l16];
    float sS[STATS ? NT : 1] = {0.f}, sQ[STATS ? NT : 1] = {0.f};

    float run0 = 0.f, run1 = 0.f;            // scan carries (lane cols 2l, 2l+1)
    const int sc_r = lane >> 2;              // scan content chunk
    const int sc_b = (lane & 3) * 4;         // byte within chunk (2 adjacent cols)

    uint4 cur[8], nxt[8];
    {
        const uint4* p = (const uint4*)(Yin + (size_t)row0 * 128);
        #pragma unroll
        for (int u = 0; u < 8; ++u) cur[u] = p[u * 64 + lane];
    }

    for (int t = 0; t < 8; ++t) {
        if (t < 7) {   // reg-prefetch next 32-row tile (full iteration to cover latency)
            const uint4* p = (const uint4*)(Yin + (size_t)(row0 + (t + 1) * 32) * 128);
            #pragma unroll
            for (int u = 0; u < 8; ++u) nxt[u] = p[u * 64 + lane];
        }

        // ---- act on current tile -> private LDS (XOR-swizzled 32x256B) ----
        #pragma unroll
        for (int u = 0; u < 8; ++u) {
            ushort_t e[8];
            *(uint4*)e = cur[u];
            uint_t w[4];
            #pragma unroll
            for (int z = 0; z < 4; ++z)
                w[z] = pack2(fmaxf(fmaf(b2f(e[2 * z]),     scr[2 * z],     shr[2 * z]),     0.f),
                             fmaxf(fmaf(b2f(e[2 * z + 1]), scr[2 * z + 1], shr[2 * z + 1]), 0.f));
            int ru = u * 4 + (lane >> 4);
            *(uint4*)(AWb + ru * 256 + ((l16 ^ (ru & 15)) & 15) * 16) = *(uint4*)w;
        }
        LGKM0;   // act tile committed before own-wave reads

        float4_t acc[2][NT];
        #pragma unroll
        for (int mt = 0; mt < 2; ++mt)
            #pragma unroll
            for (int nt = 0; nt < NT; ++nt) acc[mt][nt] = (float4_t)0.f;

        auto do_mfma = [&](int cbase) {
            #pragma unroll
            for (int kk = 0; kk < 4; ++kk) {
                int j = kk * 4 + quad;
                short8_t a0 = *(const short8_t*)(AWb + l16 * 256 + ((j ^ l16) & 15) * 16);
                short8_t a1 = *(const short8_t*)(AWb + (16 + l16) * 256 + ((j ^ l16) & 15) * 16);
                #pragma unroll
                for (int nt = 0; nt < NT; ++nt) {
                    int br = nh * NH + nt * 16 + l16;
                    const char* bp = (const char*)sm.Ws + (size_t)br * (KW * 2) +
                                     ((cbase | ((j ^ (br & 15)) & 15))) * 16;
                    short8_t bf = *(const short8_t*)bp;
                    acc[0][nt] = __builtin_amdgcn_mfma_f32_16x16x32_bf16(a0, bf, acc[0][nt], 0, 0, 0);
                    acc[1][nt] = __builtin_amdgcn_mfma_f32_16x16x32_bf16(a1, bf, acc[1][nt], 0, 0, 0);
                }
            }
        };

        if constexpr (CONCAT) {   // L1 kt0: act half of K
            do_mfma(0);
            LGKM0;                // frag reads done before in-place scan writes
        }

        if constexpr (SCAN) {
            // in-lane serial cummax: lane owns cols 2l, 2l+1; carries in regs.
            uint_t sv[32];
            #pragma unroll
            for (int r = 0; r < 32; ++r)
                sv[r] = *(const uint_t*)(AWb + r * 256 + ((sc_r ^ (r & 15)) & 15) * 16 + sc_b);
            #pragma unroll
            for (int r = 0; r < 32; ++r) {
                run0 = fmaxf(run0, b2f((ushort_t)(sv[r] & 0xffff)));
                run1 = fmaxf(run1, b2f((ushort_t)(sv[r] >> 16)));
                *(uint_t*)(AWb + r * 256 + ((sc_r ^ (r & 15)) & 15) * 16 + sc_b) = pack2(run0, run1);
            }
            LGKM0;                // P committed before own-wave frag reads
        }

        // main MFMA: P (scan phases) or act (L2/L4); L1 uses K-half 2 of Ws
        do_mfma(CONCAT ? 16 : 0);
        LGKM0;                    // frag reads done before epilogue overwrite

        // ---- epilogue: bias + stats + swizzled bounce (16 x 256B layout) ----
        #pragma unroll
        for (int mt = 0; mt < 2; ++mt)
            #pragma unroll
            for (int nt = 0; nt < NT; ++nt)
                #pragma unroll
                for (int rr = 0; rr < 4; ++rr) {
                    float v = acc[mt][nt][rr] + bvs[nt];
                    if constexpr (STATS) { sS[nt] += v; sQ[nt] = fmaf(v, v, sQ[nt]); }
                    int row = mt * 16 + quad * 4 + rr;
                    int cb = (nt * 16 + l16) * (OUTF32 ? 4 : 2);
                    int dr = row >> 1;
                    int ch = (cb >> 4) | ((row & 1) << 3);
                    char* a = AWb + dr * 256 + ((ch ^ (dr & 15)) & 15) * 16 + (cb & 15);
                    if constexpr (OUTF32) *(float*)a = v;
                    else                  *(ushort_t*)a = f2b(v);
                }
        LGKM0;   // epi tile committed

        // ---- coalesced stores: 128B segments; row stride 256B both dtypes ----
        {
            size_t gr0 = (size_t)row0 + (size_t)t * 32;
            #pragma unroll
            for (int p2 = 0; p2 < 4; ++p2) {
                int gidx = p2 * 64 + lane;
                int dr = gidx >> 4, ch = gidx & 15;
                uint4 v = *(const uint4*)(AWb + dr * 256 + ((ch ^ (dr & 15)) & 15) * 16);
                *(uint4*)(Yout + (gr0 + dr * 2 + (ch >> 3)) * 256 + nh * 128 + (ch & 7) * 16) = v;
            }
        }
        LGKM0;   // store-side ds_reads done before next tile's act writes

        if (t < 7) {
            #pragma unroll
            for (int u = 0; u < 8; ++u) cur[u] = nxt[u];
        }
    }

    if constexpr (STATS) {
        #pragma unroll
        for (int nt = 0; nt < NT; ++nt) {
            float s = sS[nt], q = sQ[nt];
            s += __shfl_xor(s, 16); q += __shfl_xor(q, 16);
            s += __shfl_xor(s, 32); q += __shfl_xor(q, 32);
            if (lane < 16) {
                int cl = nt * 16 + l16;
                sm.sred[(wave * 64 + cl) * 2 + 0] = s;
                sm.sred[(wave * 64 + cl) * 2 + 1] = q;
            }
        }
        __syncthreads();
        if (tid < 256) {
            int col = tid & 127, qs = tid >> 7;
            int nhc = col >> 6, cl = col & 63;
            float v = 0.f;
            #pragma unroll
            for (int s4 = 0; s4 < 4; ++s4)
                v += sm.sred[((s4 * 2 + nhc) * 64 + cl) * 2 + qs];
            atomicAdd(accum + qs * 128 + col, v);
        }
    }
}

__launch_bounds__(512, 2)
__global__ void fused_k(ushort_t* h0, ushort_t* h1,
                        const ushort_t* wt1, const ushort_t* wt2,
                        const ushort_t* wt3, const ushort_t* wt4,
                        const float* b1, const float* b2, const float* b3, const float* b4,
                        const float* g1, const float* be1, const float* g2, const float* be2,
                        const float* g3, const float* be3,
                        const float* sc0, const float* sh0,
                        float* accum, float* out, unsigned* cnts) {
    __shared__ SmemT sm;
    const int blockRow0 = blockIdx.x * 1024;  // 4 sequences per block

    if (threadIdx.x < 128) {
        sm.s_sc[threadIdx.x] = sc0[threadIdx.x];
        sm.s_sh[threadIdx.x] = sh0[threadIdx.x];
    }
    // (visibility guaranteed by phase_run's staging barrier)

    // L1: y1 = [bnrelu0(y0), cummax(bnrelu0(y0))] @ W1 + b1   (h0 -> h1)
    phase_run<256, 128, true, true, true, false>(sm, h0, (char*)h1, wt1, b1, accum, blockRow0);
    grid_sync(cnts + 0);
    compute_scsh(sm, accum, g1, be1);
    // L2: y2 = bnrelu1(y1) @ W2 + b2                          (h1 -> h0)
    phase_run<128, 128, false, false, true, false>(sm, h1, (char*)h0, wt2, b2, accum + 256, blockRow0);
    grid_sync(cnts + 1);
    compute_scsh(sm, accum + 256, g2, be2);
    // L3: y3 = cummax(bnrelu2(y2)) @ W3 + b3                  (h0 -> h1)
    phase_run<128, 128, true, false, true, false>(sm, h0, (char*)h1, wt3, b3, accum + 512, blockRow0);
    grid_sync(cnts + 2);
    compute_scsh(sm, accum + 512, g3, be3);
    // L4: out = bnrelu3(y3) @ W4 + b4 (fp32)                  (h1 -> out)
    phase_run<128, 64, false, false, false, true>(sm, h1, (char*)out, wt4, b4, nullptr, blockRow0);
}

// ---------------------------------------------------------------------------
// fp32 vector GEMM (layer 0: K=32, fp32 input) with fused stats partials.
// ---------------------------------------------------------------------------
template<int K, int N>
__launch_bounds__(256)
__global__ void gemm_f32_k(const float* __restrict__ A, const float* __restrict__ W,
                           const float* __restrict__ bias, ushort_t* __restrict__ C,
                           float* __restrict__ sumP, float* __restrict__ sqP) {
    constexpr int TX = N / 4;        // 32
    constexpr int TY = 256 / TX;     // 8
    constexpr int RM = TILE_M / TY;  // 8

    __shared__ float As[TILE_M][BK + 1];
    __shared__ float Ws[BK][N];
    __shared__ float redst[2][TY][N];

    const int tid = threadIdx.x;
    const int tx = tid % TX;
    const int ty = tid / TX;
    const int row0 = blockIdx.x * TILE_M;
    const int arow = tid >> 2;
    const int acol = (tid & 3) * 8;

    float acc[RM][4];
    #pragma unroll
    for (int r = 0; r < RM; ++r)
        #pragma unroll
        for (int c = 0; c < 4; ++c) acc[r][c] = 0.f;

    for (int k0 = 0; k0 < K; k0 += BK) {
        {
            const float4* p = (const float4*)&A[(size_t)(row0 + arow) * K + k0 + acol];
            float4 x0 = p[0], x1 = p[1];
            As[arow][acol + 0] = x0.x; As[arow][acol + 1] = x0.y;
            As[arow][acol + 2] = x0.z; As[arow][acol + 3] = x0.w;
            As[arow][acol + 4] = x1.x; As[arow][acol + 5] = x1.y;
            As[arow][acol + 6] = x1.z; As[arow][acol + 7] = x1.w;
        }
        #pragma unroll
        for (int i = 0; i < (BK * N) / 256; ++i) {
            int e = i * 256 + tid;
            Ws[e / N][e % N] = W[(size_t)(k0 + e / N) * N + e % N];
        }
        __syncthreads();
        #pragma unroll
        for (int kk = 0; kk < BK; ++kk) {
            float4 wv = *(const float4*)&Ws[kk][tx * 4];
            #pragma unroll
            for (int r = 0; r < RM; ++r) {
                float a = As[ty * RM + r][kk];
                acc[r][0] = fmaf(a, wv.x, acc[r][0]);
                acc[r][1] = fmaf(a, wv.y, acc[r][1]);
                acc[r][2] = fmaf(a, wv.z, acc[r][2]);
                acc[r][3] = fmaf(a, wv.w, acc[r][3]);
            }
        }
        __syncthreads();
    }
    float4 bv = *(const float4*)&bias[tx * 4];
    float s[4] = {0, 0, 0, 0}, q[4] = {0, 0, 0, 0};
    #pragma unroll
    for (int r = 0; r < RM; ++r) {
        float o[4];
        o[0] = acc[r][0] + bv.x; o[1] = acc[r][1] + bv.y;
        o[2] = acc[r][2] + bv.z; o[3] = acc[r][3] + bv.w;
        #pragma unroll
        for (int c = 0; c < 4; ++c) { s[c] += o[c]; q[c] = fmaf(o[c], o[c], q[c]); }
        size_t off = (size_t)(row0 + ty * RM + r) * N + tx * 4;
        uint2 ov;
        ov.x = pack2(o[0], o[1]);
        ov.y = pack2(o[2], o[3]);
        *(uint2*)&C[off] = ov;
    }
    #pragma unroll
    for (int c = 0; c < 4; ++c) {
        redst[0][ty][tx * 4 + c] = s[c];
        redst[1][ty][tx * 4 + c] = q[c];
    }
    __syncthreads();
    {
        int col = tid & (N - 1), qs = tid / N;
        float v = 0.f;
        #pragma unroll
        for (int t = 0; t < TY; ++t) v += redst[qs][t][col];
        (qs ? sqP : sumP)[(size_t)blockIdx.x * N + col] = v;
    }
}

// ---------------------------------------------------------------------------
// Tree-reduce block partials: P[NBLK][128] -> R2[col*64 + chunk] (64 chunks).
// ---------------------------------------------------------------------------
template<int NBLK>
__global__ __launch_bounds__(256) void reduce1_k(const float* __restrict__ sumP,
                                                 const float* __restrict__ sqP,
                                                 float* __restrict__ sumR2,
                                                 float* __restrict__ sqR2) {
    constexpr int ROWS = NBLK / 64;
    const int tid = threadIdx.x;
    const int qs = blockIdx.x & 1;
    const int chunk = blockIdx.x >> 1;
    const float* src = qs ? sqP : sumP;
    float* dst = qs ? sqR2 : sumR2;
    const int col = tid & 127;
    const int half = tid >> 7;
    float s = 0.f;
    for (int r = half; r < ROWS; r += 2)
        s += src[(size_t)(chunk * ROWS + r) * 128 + col];
    __shared__ float red[256];
    red[tid] = s;
    __syncthreads();
    if (tid < 128) dst[col * 64 + chunk] = red[tid] + red[tid + 128];
}

// Reduce 64 chunks; scale = g*rsqrt(var+eps); shift = be - mean*scale
__global__ void finalize_k(const float* __restrict__ sumR2, const float* __restrict__ sqR2,
                           const float* __restrict__ g, const float* __restrict__ be,
                           float* __restrict__ scale, float* __restrict__ shift) {
    const int f = threadIdx.x;  // 128
    const float4* ps = (const float4*)&sumR2[f * REP];
    const float4* pq = (const float4*)&sqR2[f * REP];
    float s = 0.f, q = 0.f;
    #pragma unroll
    for (int i = 0; i < REP / 4; ++i) {
        float4 a = ps[i]; s += (a.x + a.y) + (a.z + a.w);
        float4 b = pq[i]; q += (b.x + b.y) + (b.z + b.w);
    }
    const float invM = 1.f / (float)M_ROWS;
    float mean = s * invM;
    float var = q * invM - mean * mean;
    float sc = g[f] * rsqrtf(var + 1e-5f);
    scale[f] = sc;
    shift[f] = fmaf(-mean, sc, be[f]);
}

// All four weight transposes in one launch: fp32 W[K][N] -> bf16 WT[N][K]
__global__ void transpose_all_k(const float* __restrict__ W1, const float* __restrict__ W2,
                                const float* __restrict__ W3, const float* __restrict__ W4,
                                ushort_t* __restrict__ wt1, ushort_t* __restrict__ wt2,
                                ushort_t* __restrict__ wt3, ushort_t* __restrict__ wt4) {
    int idx = blockIdx.x * 256 + threadIdx.x;
    if (idx < 32768) {                       // W1: 256 x 128
        int k = idx >> 7, n = idx & 127;
        wt1[(size_t)n * 256 + k] = f2b(W1[idx]);
    } else if (idx < 49152) {                // W2: 128 x 128
        int i = idx - 32768;
        int k = i >> 7, n = i & 127;
        wt2[(size_t)n * 128 + k] = f2b(W2[i]);
    } else if (idx < 65536) {                // W3: 128 x 128
        int i = idx - 49152;
        int k = i >> 7, n = i & 127;
        wt3[(size_t)n * 128 + k] = f2b(W3[i]);
    } else if (idx < 73728) {                // W4: 128 x 64
        int i = idx - 65536;
        int k = i >> 6, n = i & 63;
        wt4[(size_t)n * 128 + k] = f2b(W4[i]);
    }
}

extern "C" void kernel_launch(void* const* d_in, const int* in_sizes, int n_in,
                              void* d_out, int out_size, void* d_ws, size_t ws_size,
                              hipStream_t stream) {
    const float* poly = (const float*)d_in[0];
    const float* W0 = (const float*)d_in[1];
    const float* b0 = (const float*)d_in[2];
    const float* g0 = (const float*)d_in[3];
    const float* be0 = (const float*)d_in[4];
    const float* W1 = (const float*)d_in[5];
    const float* b1 = (const float*)d_in[6];
    const float* g1 = (const float*)d_in[7];
    const float* be1 = (const float*)d_in[8];
    const float* W2 = (const float*)d_in[9];
    const float* b2 = (const float*)d_in[10];
    const float* g2 = (const float*)d_in[11];
    const float* be2 = (const float*)d_in[12];
    const float* W3 = (const float*)d_in[13];
    const float* b3 = (const float*)d_in[14];
    const float* g3 = (const float*)d_in[15];
    const float* be3 = (const float*)d_in[16];
    const float* W4 = (const float*)d_in[17];
    const float* b4 = (const float*)d_in[18];
    float* outp = (float*)d_out;

    float* st = (float*)d_ws;
    float* sumP = st;
    float* sqP = st + 524288;
    float* sumR2 = st + 1048576;
    float* sqR2 = sumR2 + 8192;
    float* scsh = st + 1064960;
    ushort_t* wt1 = (ushort_t*)((char*)d_ws + 4263936);         // 128 x 256
    ushort_t* wt2 = wt1 + 128 * 256;                            // 128 x 128
    ushort_t* wt3 = wt2 + 128 * 128;                            // 128 x 128
    ushort_t* wt4 = wt3 + 128 * 128;                            // 64 x 128
    ushort_t* h0 = (ushort_t*)((char*)d_ws + 4263936 + 147456);
    ushort_t* h1 = h0 + (size_t)M_ROWS * 128;

    const int G64 = M_ROWS / TILE_M;    // 4096 (L0)

    transpose_all_k<<<288, 256, 0, stream>>>(W1, W2, W3, W4, wt1, wt2, wt3, wt4);

    // Layer 0 (fp32 precision): y0 = poly @ W0 + b0 -> h0 (raw bf16) + partials
    gemm_f32_k<32, 128><<<G64, 256, 0, stream>>>(poly, W0, b0, h0, sumP, sqP);
    reduce1_k<4096><<<128, 256, 0, stream>>>(sumP, sqP, sumR2, sqR2);
    finalize_k<<<1, 128, 0, stream>>>(sumR2, sqR2, g0, be0, scsh, scsh + 128);

    // zero fused-kernel stat accumulators (3 layers x 256) + 3 barrier counters
    hipMemsetAsync(sumR2, 0, (768 + 8) * sizeof(float), stream);
    float* accum = sumR2;
    unsigned* cnts = (unsigned*)(sumR2 + 768);
    const float* sc0 = scsh;
    const float* sh0 = scsh + 128;

    // Persistent cooperative kernel: L1..L4 + both scans + all BN stats
    void* args[] = { &h0, &h1, &wt1, &wt2, &wt3, &wt4,
                     &b1, &b2, &b3, &b4,
                     &g1, &be1, &g2, &be2, &g3, &be3,
                     &sc0, &sh0, &accum, &outp, &cnts };
    hipLaunchCooperativeKernel((void*)fused_k, dim3(NBLOCKS), dim3(512), args, 0, stream);
}